// Round 4
// baseline (904.309 us; speedup 1.0000x reference)
//
#include <hip/hip_runtime.h>
#include <cstdint>
#include <cstddef>

#define Tn 1024
#define Hn 2048
#define En 8
#define In 1408
#define ISn 5632

typedef __attribute__((ext_vector_type(8))) short bf16x8;
typedef __attribute__((ext_vector_type(4))) float f32x4;

__device__ __forceinline__ unsigned short f2bf(float f) {
  unsigned u = __builtin_bit_cast(unsigned, f);
  u += 0x7fffu + ((u >> 16) & 1u);
  return (unsigned short)(u >> 16);
}

#define PK2(a, b) ((unsigned)f2bf(a) | ((unsigned)f2bf(b) << 16))
// LDS layout: [row:128][k:64] bf16, 128B rows; 16B chunk index XOR-swizzled so
// every 16-lane phase of ds_read_b128/ds_write_b128 is 2-way max (free, m136).
#define SWZC(row, kc) (((kc) ^ ((row) & 7) ^ (((row) >> 3) & 7)) & 7)
#define SWZ(row, bir) (((row) << 7) | (SWZC((row), ((bir) >> 4)) << 4) | ((bir) & 15))

// ------- router: fp32 logits/softmax/top-2; builds per-expert compact lists --
__global__ void router_kernel(const float* __restrict__ x, const float* __restrict__ gw,
                              const float* __restrict__ sgw, float* __restrict__ logits_out,
                              float* __restrict__ sgate, int* __restrict__ tokList,
                              float* __restrict__ wgt, int* __restrict__ cnt) {
  int t = blockIdx.x;
  int l = threadIdx.x;
  const float* xr = x + (size_t)t * Hn;
  float acc[En];
#pragma unroll
  for (int e = 0; e < En; ++e) acc[e] = 0.f;
  float accs = 0.f;
  for (int h = l; h < Hn; h += 64) {
    float xv = xr[h];
    const float4 g0 = *(const float4*)(gw + (size_t)h * En);
    const float4 g1 = *(const float4*)(gw + (size_t)h * En + 4);
    acc[0] += xv * g0.x; acc[1] += xv * g0.y; acc[2] += xv * g0.z; acc[3] += xv * g0.w;
    acc[4] += xv * g1.x; acc[5] += xv * g1.y; acc[6] += xv * g1.z; acc[7] += xv * g1.w;
    accs += xv * sgw[h];
  }
#pragma unroll
  for (int e = 0; e < En; ++e) {
#pragma unroll
    for (int off = 32; off > 0; off >>= 1) acc[e] += __shfl_down(acc[e], off);
  }
#pragma unroll
  for (int off = 32; off > 0; off >>= 1) accs += __shfl_down(accs, off);
  if (l == 0) {
    float mx = acc[0];
#pragma unroll
    for (int e = 1; e < En; ++e) mx = fmaxf(mx, acc[e]);
    float p[En], s = 0.f;
#pragma unroll
    for (int e = 0; e < En; ++e) { p[e] = expf(acc[e] - mx); s += p[e]; }
    float inv = 1.f / s;
#pragma unroll
    for (int e = 0; e < En; ++e) p[e] *= inv;
    int i1 = 0;
#pragma unroll
    for (int e = 1; e < En; ++e) if (p[e] > p[i1]) i1 = e;     // strict >: lowest idx wins ties
    int i2 = (i1 == 0) ? 1 : 0;
#pragma unroll
    for (int e = 0; e < En; ++e) if (e != i1 && p[e] > p[i2]) i2 = e;
    int p1 = atomicAdd(&cnt[i1], 1);
    tokList[(i1 << 10) + p1] = t; wgt[(i1 << 10) + p1] = p[i1];
    int p2 = atomicAdd(&cnt[i2], 1);
    tokList[(i2 << 10) + p2] = t; wgt[(i2 << 10) + p2] = p[i2];
    sgate[t] = 1.f / (1.f + expf(-accs));
#pragma unroll
    for (int e = 0; e < En; ++e) logits_out[t * En + e] = acc[e];
  }
}

// ---------------- x -> bf16 ----------------
__global__ void cvt_x_kernel(const float* __restrict__ x, unsigned short* __restrict__ xb) {
  int i = (blockIdx.x * 256 + threadIdx.x) << 2;
  float4 v = *(const float4*)(x + i);
  ushort4 o;
  o.x = f2bf(v.x); o.y = f2bf(v.y); o.z = f2bf(v.z); o.w = f2bf(v.w);
  *(ushort4*)(xb + i) = o;
}

// Stage a 64k x 128n fp32 tile -> LDS as B^T [128n][64k] bf16, swizzled.
__device__ __forceinline__ void stage_b(char* sB, const float* __restrict__ src, int ldb, int tid) {
  const int kb = tid >> 5;      // 0..7  (k-chunk of 8)
  const int nb = tid & 31;      // 0..31 (n-chunk of 4)
  const float* p = src + (size_t)(kb * 8) * ldb + nb * 4;
  float4 r0 = *(const float4*)p; p += ldb;
  float4 r1 = *(const float4*)p; p += ldb;
  float4 r2 = *(const float4*)p; p += ldb;
  float4 r3 = *(const float4*)p; p += ldb;
  float4 r4 = *(const float4*)p; p += ldb;
  float4 r5 = *(const float4*)p; p += ldb;
  float4 r6 = *(const float4*)p; p += ldb;
  float4 r7 = *(const float4*)p;
  uint4 pk;
  int n, off;
#define STORE_ROW(J, F)                                                        \
  n = nb * 4 + (J);                                                            \
  pk.x = PK2(r0.F, r1.F); pk.y = PK2(r2.F, r3.F);                              \
  pk.z = PK2(r4.F, r5.F); pk.w = PK2(r6.F, r7.F);                              \
  off = (n << 7) | (SWZC(n, kb) << 4);                                         \
  *(uint4*)(sB + off) = pk;
  STORE_ROW(0, x)
  STORE_ROW(1, y)
  STORE_ROW(2, z)
  STORE_ROW(3, w)
#undef STORE_ROW
}

// ------- fused gate/up GEMM over compact token rows -------------------------
// mode 0: expert e = blockIdx.y, rows = tokList[e][0..cnt), scale = wgt
// mode 1: shared expert, rows = all tokens, scale = sgate
// grid.x = ntiles*8, mt = blockIdx.x&7 fastest (panel-sharing blocks adjacent)
__global__ __launch_bounds__(256, 2)
void gateup_kernel(const unsigned short* __restrict__ xb,
                   const float* __restrict__ Wg, const float* __restrict__ Wu,
                   const float* __restrict__ wgt, const float* __restrict__ sgate,
                   const int* __restrict__ tokList, const int* __restrict__ cnt,
                   unsigned short* __restrict__ actout, int N, int mode) {
  const int e = blockIdx.y;
  const int nt = blockIdx.x >> 3, mt = blockIdx.x & 7;
  const int cntE = (mode == 0) ? cnt[e] : Tn;
  const int m0 = mt << 7, n0 = nt << 7;
  if (m0 >= cntE) return;

  __shared__ char smem[48 * 1024];
  char* sA = smem;
  char* sBg = smem + 16 * 1024;
  char* sBu = smem + 32 * 1024;

  const int tid = threadIdx.x;
  const int lane = tid & 63;
  const int wid = tid >> 6;
  const int wm = wid >> 1, wn = wid & 1;

  const float* Bg0 = Wg + (size_t)e * Hn * N + n0;
  const float* Bu0 = Wu + (size_t)e * Hn * N + n0;
  unsigned short* aout = actout + (size_t)e * Tn * N;

  // per-thread gathered token for each of the 4 A-stage rows
  int tokq[4];
#pragma unroll
  for (int q = 0; q < 4; ++q) {
    int row = (tid + (q << 8)) >> 3;
    int m = m0 + row;
    if (mode == 0) {
      int mc = m < cntE ? m : cntE - 1;
      tokq[q] = tokList[(e << 10) + mc];
    } else {
      tokq[q] = m;
    }
  }

  f32x4 accg[4][4], accu[4][4];
#pragma unroll
  for (int i = 0; i < 4; ++i)
#pragma unroll
    for (int j = 0; j < 4; ++j) {
      accg[i][j] = {0.f, 0.f, 0.f, 0.f};
      accu[i][j] = {0.f, 0.f, 0.f, 0.f};
    }

  for (int kt = 0; kt < Hn / 64; ++kt) {
    const int k0 = kt << 6;
#pragma unroll
    for (int q = 0; q < 4; ++q) {
      int cc = tid + (q << 8);
      int row = cc >> 3, c = cc & 7;
      uint4 v = *(const uint4*)(xb + (size_t)tokq[q] * Hn + k0 + (c << 3));
      *(uint4*)(sA + SWZ(row, c << 4)) = v;
    }
    stage_b(sBg, Bg0 + (size_t)k0 * N, N, tid);
    stage_b(sBu, Bu0 + (size_t)k0 * N, N, tid);
    __syncthreads();
#pragma unroll
    for (int kk = 0; kk < 2; ++kk) {
      bf16x8 af[4], bg[4], bu[4];
      const int bir = (kk << 6) + ((lane >> 4) << 4);
#pragma unroll
      for (int mi = 0; mi < 4; ++mi) {
        int row = (wm << 6) + (mi << 4) + (lane & 15);
        af[mi] = *(const bf16x8*)(sA + SWZ(row, bir));
      }
#pragma unroll
      for (int ni = 0; ni < 4; ++ni) {
        int n = (wn << 6) + (ni << 4) + (lane & 15);
        bg[ni] = *(const bf16x8*)(sBg + SWZ(n, bir));
        bu[ni] = *(const bf16x8*)(sBu + SWZ(n, bir));
      }
#pragma unroll
      for (int mi = 0; mi < 4; ++mi)
#pragma unroll
        for (int ni = 0; ni < 4; ++ni) {
          accg[mi][ni] = __builtin_amdgcn_mfma_f32_16x16x32_bf16(af[mi], bg[ni], accg[mi][ni], 0, 0, 0);
          accu[mi][ni] = __builtin_amdgcn_mfma_f32_16x16x32_bf16(af[mi], bu[ni], accu[mi][ni], 0, 0, 0);
        }
    }
    __syncthreads();
  }

#pragma unroll
  for (int mi = 0; mi < 4; ++mi)
#pragma unroll
    for (int ni = 0; ni < 4; ++ni)
#pragma unroll
      for (int r = 0; r < 4; ++r) {
        int m = m0 + (wm << 6) + (mi << 4) + ((lane >> 4) << 2) + r;
        int n = n0 + (wn << 6) + (ni << 4) + (lane & 15);
        if (m < cntE) {
          float sc = (mode == 0) ? wgt[(e << 10) + m] : sgate[m];
          float g = accg[mi][ni][r];
          float u = accu[mi][ni][r];
          aout[(size_t)m * N + n] = f2bf(sc * (g / (1.f + __expf(-g))) * u);
        }
      }
}

// ------- expert down: out[tok] += act_e @ wd_e  (scatter atomicAdd) ---------
__global__ __launch_bounds__(256, 2)
void down_e_kernel(const unsigned short* __restrict__ act, const float* __restrict__ wd,
                   const int* __restrict__ tokList, const int* __restrict__ cnt,
                   float* __restrict__ out) {
  const int e = blockIdx.y;
  const int nt = blockIdx.x >> 3, mt = blockIdx.x & 7;
  const int cntE = cnt[e];
  const int m0 = mt << 7, n0 = nt << 7;
  if (m0 >= cntE) return;

  __shared__ char smem[32 * 1024];
  char* sA = smem;
  char* sB = smem + 16 * 1024;

  const int tid = threadIdx.x;
  const int lane = tid & 63;
  const int wid = tid >> 6;
  const int wm = wid >> 1, wn = wid & 1;

  const unsigned short* aBase = act + ((size_t)e * Tn + m0) * In;
  const float* bBase = wd + (size_t)e * In * Hn + n0;

  f32x4 acc[4][4];
#pragma unroll
  for (int i = 0; i < 4; ++i)
#pragma unroll
    for (int j = 0; j < 4; ++j) acc[i][j] = {0.f, 0.f, 0.f, 0.f};

  for (int kt = 0; kt < In / 64; ++kt) {
    const int k0 = kt << 6;
#pragma unroll
    for (int q = 0; q < 4; ++q) {
      int cc = tid + (q << 8);
      int row = cc >> 3, c = cc & 7;
      uint4 v = *(const uint4*)(aBase + (size_t)row * In + k0 + (c << 3));
      *(uint4*)(sA + SWZ(row, c << 4)) = v;
    }
    stage_b(sB, bBase + (size_t)k0 * Hn, Hn, tid);
    __syncthreads();
#pragma unroll
    for (int kk = 0; kk < 2; ++kk) {
      bf16x8 af[4], bf[4];
      const int bir = (kk << 6) + ((lane >> 4) << 4);
#pragma unroll
      for (int mi = 0; mi < 4; ++mi) {
        int row = (wm << 6) + (mi << 4) + (lane & 15);
        af[mi] = *(const bf16x8*)(sA + SWZ(row, bir));
      }
#pragma unroll
      for (int ni = 0; ni < 4; ++ni) {
        int n = (wn << 6) + (ni << 4) + (lane & 15);
        bf[ni] = *(const bf16x8*)(sB + SWZ(n, bir));
      }
#pragma unroll
      for (int mi = 0; mi < 4; ++mi)
#pragma unroll
        for (int ni = 0; ni < 4; ++ni)
          acc[mi][ni] = __builtin_amdgcn_mfma_f32_16x16x32_bf16(af[mi], bf[ni], acc[mi][ni], 0, 0, 0);
    }
    __syncthreads();
  }

#pragma unroll
  for (int mi = 0; mi < 4; ++mi)
#pragma unroll
    for (int ni = 0; ni < 4; ++ni)
#pragma unroll
      for (int r = 0; r < 4; ++r) {
        int m = m0 + (wm << 6) + (mi << 4) + ((lane >> 4) << 2) + r;
        int n = n0 + (wn << 6) + (ni << 4) + (lane & 15);
        if (m < cntE) {
          int tok = tokList[(e << 10) + m];
          atomicAdd(out + (size_t)tok * Hn + n, acc[mi][ni][r]);
        }
      }
}

// ------- shared down: out += actS @ sd, split-K=2, atomicAdd ----------------
__global__ __launch_bounds__(256, 2)
void down_s_kernel(const unsigned short* __restrict__ acts, const float* __restrict__ sd,
                   float* __restrict__ out) {
  const int nt = blockIdx.x >> 3, mt = blockIdx.x & 7;
  const int m0 = mt << 7, n0 = nt << 7;
  const int ktBeg = blockIdx.y * 44, ktEnd = ktBeg + 44;

  __shared__ char smem[32 * 1024];
  char* sA = smem;
  char* sB = smem + 16 * 1024;

  const int tid = threadIdx.x;
  const int lane = tid & 63;
  const int wid = tid >> 6;
  const int wm = wid >> 1, wn = wid & 1;

  f32x4 acc[4][4];
#pragma unroll
  for (int i = 0; i < 4; ++i)
#pragma unroll
    for (int j = 0; j < 4; ++j) acc[i][j] = {0.f, 0.f, 0.f, 0.f};

  for (int kt = ktBeg; kt < ktEnd; ++kt) {
    const int k0 = kt << 6;
#pragma unroll
    for (int q = 0; q < 4; ++q) {
      int cc = tid + (q << 8);
      int row = cc >> 3, c = cc & 7;
      uint4 v = *(const uint4*)(acts + (size_t)(m0 + row) * ISn + k0 + (c << 3));
      *(uint4*)(sA + SWZ(row, c << 4)) = v;
    }
    stage_b(sB, sd + (size_t)k0 * Hn + n0, Hn, tid);
    __syncthreads();
#pragma unroll
    for (int kk = 0; kk < 2; ++kk) {
      bf16x8 af[4], bf[4];
      const int bir = (kk << 6) + ((lane >> 4) << 4);
#pragma unroll
      for (int mi = 0; mi < 4; ++mi) {
        int row = (wm << 6) + (mi << 4) + (lane & 15);
        af[mi] = *(const bf16x8*)(sA + SWZ(row, bir));
      }
#pragma unroll
      for (int ni = 0; ni < 4; ++ni) {
        int n = (wn << 6) + (ni << 4) + (lane & 15);
        bf[ni] = *(const bf16x8*)(sB + SWZ(n, bir));
      }
#pragma unroll
      for (int mi = 0; mi < 4; ++mi)
#pragma unroll
        for (int ni = 0; ni < 4; ++ni)
          acc[mi][ni] = __builtin_amdgcn_mfma_f32_16x16x32_bf16(af[mi], bf[ni], acc[mi][ni], 0, 0, 0);
    }
    __syncthreads();
  }

#pragma unroll
  for (int mi = 0; mi < 4; ++mi)
#pragma unroll
    for (int ni = 0; ni < 4; ++ni)
#pragma unroll
      for (int r = 0; r < 4; ++r) {
        int m = m0 + (wm << 6) + (mi << 4) + ((lane >> 4) << 2) + r;
        int n = n0 + (wn << 6) + (ni << 4) + (lane & 15);
        atomicAdd(out + (size_t)m * Hn + n, acc[mi][ni][r]);
      }
}

extern "C" void kernel_launch(void* const* d_in, const int* in_sizes, int n_in,
                              void* d_out, int out_size, void* d_ws, size_t ws_size,
                              hipStream_t stream) {
  const float* x   = (const float*)d_in[0];
  const float* gw  = (const float*)d_in[1];
  const float* wg  = (const float*)d_in[2];
  const float* wu  = (const float*)d_in[3];
  const float* wd  = (const float*)d_in[4];
  const float* sg  = (const float*)d_in[5];
  const float* su  = (const float*)d_in[6];
  const float* sd  = (const float*)d_in[7];
  const float* sgw = (const float*)d_in[8];
  float* out = (float*)d_out;
  float* logits_out = out + (size_t)Tn * Hn;   // final [2,512,2048] then logits [1024,8]

  char* w = (char*)d_ws;
  int*   cnt     = (int*)w;                                // 8 int
  float* sgate   = (float*)(w + 4096);                     // 1024 f32
  int*   tokList = (int*)(w + 8192);                       // 8192 int (32KB)
  float* wgt     = (float*)(w + 40960);                    // 8192 f32 (32KB)
  unsigned short* xb   = (unsigned short*)(w + 131072);    // T*H bf16 (4MB)
  unsigned short* actE = xb + (size_t)Tn * Hn;             // E*T*I bf16 (23.1MB)
  unsigned short* actS = actE + (size_t)En * Tn * In;      // T*IS bf16 (11.5MB)

  hipMemsetAsync(d_out, 0, (size_t)out_size * sizeof(float), stream);
  hipMemsetAsync(cnt, 0, En * sizeof(int), stream);
  router_kernel<<<Tn, 64, 0, stream>>>(x, gw, sgw, logits_out, sgate, tokList, wgt, cnt);
  cvt_x_kernel<<<(Tn * Hn / 4) / 256, 256, 0, stream>>>(x, xb);
  // expert gate/up: grid.x = nt(11) * mt(8), most mt blocks early-exit
  gateup_kernel<<<dim3((In / 128) * 8, En), 256, 0, stream>>>(xb, wg, wu, wgt, sgate, tokList, cnt, actE, In, 0);
  // shared gate/up: nt(44) * mt(8)
  gateup_kernel<<<dim3((ISn / 128) * 8, 1), 256, 0, stream>>>(xb, sg, su, wgt, sgate, tokList, cnt, actS, ISn, 1);
  // expert down: nt(16) * mt(8), scatter-add
  down_e_kernel<<<dim3(16 * 8, En), 256, 0, stream>>>(actE, wd, tokList, cnt, out);
  // shared down: nt(16) * mt(8), split-K=2
  down_s_kernel<<<dim3(16 * 8, 2), 256, 0, stream>>>(actS, sd, out);
}

// Round 7
// 780.662 us; speedup vs baseline: 1.1584x; 1.1584x over previous
//
#include <hip/hip_runtime.h>
#include <cstdint>
#include <cstddef>

#define Tn 1024
#define Hn 2048
#define En 8
#define In 1408
#define ISn 5632

typedef __attribute__((ext_vector_type(8))) short bf16x8;
typedef __attribute__((ext_vector_type(4))) float f32x4;

typedef __attribute__((address_space(3))) unsigned int lds_u32_t;
typedef __attribute__((address_space(1))) const unsigned int gbl_u32_t;
// async 16B global->LDS: per-lane global src, wave-uniform LDS base + lane*16
#define GLL16(gp, lp) __builtin_amdgcn_global_load_lds((gbl_u32_t*)(gp), (lds_u32_t*)(lp), 16, 0, 0)

__device__ __forceinline__ unsigned short f2bf(float f) {
  unsigned u = __builtin_bit_cast(unsigned, f);
  u += 0x7fffu + ((u >> 16) & 1u);
  return (unsigned short)(u >> 16);
}

// LDS tiles: [row:128][k:64] bf16 linear (global_load_lds writes linearly).
// Swizzle lives in (a) per-lane SOURCE chunk select and (b) read address —
// same involution chunk' = chunk ^ (row&7) ^ ((row>>3)&7)  (rule #21).
#define SWZC(row, kc) (((kc) ^ ((row) & 7) ^ (((row) >> 3) & 7)) & 7)
#define SWZ(row, bir) (((row) << 7) | (SWZC((row), ((bir) >> 4)) << 4) | ((bir) & 15))

// ------- router: fp32 logits/softmax/top-2; builds per-expert compact lists --
__global__ void router_kernel(const float* __restrict__ x, const float* __restrict__ gw,
                              const float* __restrict__ sgw, float* __restrict__ logits_out,
                              float* __restrict__ sgate, int* __restrict__ tokList,
                              float* __restrict__ wgt, int* __restrict__ cnt) {
  int t = blockIdx.x;
  int l = threadIdx.x;
  const float* xr = x + (size_t)t * Hn;
  float acc[En];
#pragma unroll
  for (int e = 0; e < En; ++e) acc[e] = 0.f;
  float accs = 0.f;
  for (int h = l; h < Hn; h += 64) {
    float xv = xr[h];
    const float4 g0 = *(const float4*)(gw + (size_t)h * En);
    const float4 g1 = *(const float4*)(gw + (size_t)h * En + 4);
    acc[0] += xv * g0.x; acc[1] += xv * g0.y; acc[2] += xv * g0.z; acc[3] += xv * g0.w;
    acc[4] += xv * g1.x; acc[5] += xv * g1.y; acc[6] += xv * g1.z; acc[7] += xv * g1.w;
    accs += xv * sgw[h];
  }
#pragma unroll
  for (int e = 0; e < En; ++e) {
#pragma unroll
    for (int off = 32; off > 0; off >>= 1) acc[e] += __shfl_down(acc[e], off);
  }
#pragma unroll
  for (int off = 32; off > 0; off >>= 1) accs += __shfl_down(accs, off);
  if (l == 0) {
    float mx = acc[0];
#pragma unroll
    for (int e = 1; e < En; ++e) mx = fmaxf(mx, acc[e]);
    float p[En], s = 0.f;
#pragma unroll
    for (int e = 0; e < En; ++e) { p[e] = expf(acc[e] - mx); s += p[e]; }
    float inv = 1.f / s;
#pragma unroll
    for (int e = 0; e < En; ++e) p[e] *= inv;
    int i1 = 0;
#pragma unroll
    for (int e = 1; e < En; ++e) if (p[e] > p[i1]) i1 = e;     // strict >: lowest idx wins ties
    int i2 = (i1 == 0) ? 1 : 0;
#pragma unroll
    for (int e = 0; e < En; ++e) if (e != i1 && p[e] > p[i2]) i2 = e;
    int p1 = atomicAdd(&cnt[i1], 1);
    tokList[(i1 << 10) + p1] = t; wgt[(i1 << 10) + p1] = p[i1];
    int p2 = atomicAdd(&cnt[i2], 1);
    tokList[(i2 << 10) + p2] = t; wgt[(i2 << 10) + p2] = p[i2];
    sgate[t] = 1.f / (1.f + expf(-accs));
#pragma unroll
    for (int e = 0; e < En; ++e) logits_out[t * En + e] = acc[e];
  }
}

// ---------------- x -> bf16 ----------------
__global__ void cvt_x_kernel(const float* __restrict__ x, unsigned short* __restrict__ xb) {
  int i = (blockIdx.x * 256 + threadIdx.x) << 2;
  float4 v = *(const float4*)(x + i);
  ushort4 o;
  o.x = f2bf(v.x); o.y = f2bf(v.y); o.z = f2bf(v.z); o.w = f2bf(v.w);
  *(ushort4*)(xb + i) = o;
}

// ------- one-time weight pass: fp32 [R][C] -> bf16 [C][R], 64x64 tiles ------
__global__ void trans_cvt_kernel(const float* __restrict__ wg, const float* __restrict__ wu,
                                 const float* __restrict__ wd, const float* __restrict__ sg,
                                 const float* __restrict__ su, const float* __restrict__ sd,
                                 unsigned short* __restrict__ wgT, unsigned short* __restrict__ wuT,
                                 unsigned short* __restrict__ wdT, unsigned short* __restrict__ sgT,
                                 unsigned short* __restrict__ suT, unsigned short* __restrict__ sdT) {
  __shared__ unsigned short lds[64][68];
  const int bx = blockIdx.x, tid = threadIdx.x;
  const float* src; unsigned short* dst; int R, C, tr, tc;
  if (bx < 11264) {          // wg|wu: [Hn][In] -> [In][Hn], 704 tiles per expert-matrix
    int b = (bx < 5632) ? bx : bx - 5632;
    const float* s0 = (bx < 5632) ? wg : wu;
    unsigned short* d0 = (bx < 5632) ? wgT : wuT;
    int e = b / 704, t = b - e * 704;
    src = s0 + (size_t)e * Hn * In; dst = d0 + (size_t)e * In * Hn;
    R = Hn; C = In; tr = t / 22; tc = t - tr * 22;
  } else if (bx < 16896) {   // wd: [In][Hn] -> [Hn][In]
    int b = bx - 11264; int e = b / 704, t = b - e * 704;
    src = wd + (size_t)e * In * Hn; dst = wdT + (size_t)e * Hn * In;
    R = In; C = Hn; tr = t / 32; tc = t - tr * 32;
  } else if (bx < 22528) {   // sg|su: [Hn][ISn] -> [ISn][Hn]
    int b = bx - 16896;
    src = (b < 2816) ? sg : su; dst = (b < 2816) ? sgT : suT;
    if (b >= 2816) b -= 2816;
    R = Hn; C = ISn; tr = b / 88; tc = b - tr * 88;
  } else {                   // sd: [ISn][Hn] -> [Hn][ISn]
    int b = bx - 22528;
    src = sd; dst = sdT; R = ISn; C = Hn; tr = b / 32; tc = b - tr * 32;
  }
  const int r0 = tr << 6, c0 = tc << 6;
#pragma unroll
  for (int q = 0; q < 4; ++q) {
    int r = (tid >> 4) + (q << 4);
    int c = (tid & 15) << 2;
    float4 v = *(const float4*)(src + (size_t)(r0 + r) * C + c0 + c);
    ushort4 o; o.x = f2bf(v.x); o.y = f2bf(v.y); o.z = f2bf(v.z); o.w = f2bf(v.w);
    *(ushort4*)&lds[r][c] = o;
  }
  __syncthreads();
  {
    int oc = tid >> 2, ch = tid & 3;
    // 64 rows = 8 groups of 8; ch covers 4 -> two passes (g = ch, ch+4).
    // (Round-5 bug: single pass stored only rows 0..31 -> half the tile poison.)
#pragma unroll
    for (int g = ch; g < 8; g += 4) {
      unsigned t0, t1, t2, t3;
      t0 = (unsigned)lds[(g << 3) + 0][oc] | ((unsigned)lds[(g << 3) + 1][oc] << 16);
      t1 = (unsigned)lds[(g << 3) + 2][oc] | ((unsigned)lds[(g << 3) + 3][oc] << 16);
      t2 = (unsigned)lds[(g << 3) + 4][oc] | ((unsigned)lds[(g << 3) + 5][oc] << 16);
      t3 = (unsigned)lds[(g << 3) + 6][oc] | ((unsigned)lds[(g << 3) + 7][oc] << 16);
      uint4 o; o.x = t0; o.y = t1; o.z = t2; o.w = t3;
      *(uint4*)(dst + (size_t)(c0 + oc) * R + r0 + (g << 3)) = o;
    }
  }
}

// ------- fused gate/up GEMM (expert blocks [0,704) + shared blocks [704,1056)) --
// 128x128 tile, BK=64, global_load_lds staging, all operands bf16 [row][k].
__global__ __launch_bounds__(256, 2)
void gateup_kernel(const unsigned short* __restrict__ xb,
                   const unsigned short* __restrict__ wgT, const unsigned short* __restrict__ wuT,
                   const unsigned short* __restrict__ sgT, const unsigned short* __restrict__ suT,
                   const float* __restrict__ wgt, const float* __restrict__ sgate,
                   const int* __restrict__ tokList, const int* __restrict__ cnt,
                   unsigned short* __restrict__ actE, unsigned short* __restrict__ actS) {
  const int bx = blockIdx.x;
  int e, nt, mt, N, cntE, mode;
  const unsigned short *bgp, *bup;
  unsigned short* aout;
  if (bx < 704) {
    mode = 0; e = bx / 88; int r = bx - e * 88; nt = r >> 3; mt = r & 7;
    N = In; cntE = cnt[e];
    bgp = wgT + (size_t)e * In * Hn; bup = wuT + (size_t)e * In * Hn;
    aout = actE + (size_t)e * Tn * In;
  } else {
    mode = 1; e = 0; int r = bx - 704; nt = r >> 3; mt = r & 7;
    N = ISn; cntE = Tn; bgp = sgT; bup = suT; aout = actS;
  }
  const int m0 = mt << 7, n0 = nt << 7;
  if (m0 >= cntE) return;

  __shared__ char smem[48 * 1024];
  char* sA = smem;
  char* sBg = smem + 16 * 1024;
  char* sBu = smem + 32 * 1024;

  const int tid = threadIdx.x, lane = tid & 63, wid = tid >> 6;
  const int wm = wid >> 1, wn = wid & 1;
  const int qr = lane >> 3;   // sub-row 0..7 within an issue group
  const int qc = lane & 7;    // 16B chunk 0..7 within a 128B row

  // per-lane staging source addresses (4 issues per operand)
  const char *gA[4], *gB[4], *gU[4];
#pragma unroll
  for (int q = 0; q < 4; ++q) {
    int row = (wid << 5) + (q << 3) + qr;        // LDS row 0..127
    int chunk = SWZC(row, qc);                   // source-side permutation
    int m = m0 + row;
    int tok;
    if (mode == 0) { int mc = m < cntE ? m : cntE - 1; tok = tokList[(e << 10) + mc]; }
    else tok = m;
    gA[q] = (const char*)(xb + (size_t)tok * Hn) + chunk * 16;
    int n = n0 + row;
    gB[q] = (const char*)(bgp + (size_t)n * Hn) + chunk * 16;
    gU[q] = (const char*)(bup + (size_t)n * Hn) + chunk * 16;
  }
  const int lbase = wid << 12;  // wave-uniform LDS region (wid*4096)

  f32x4 accg[4][4], accu[4][4];
#pragma unroll
  for (int i = 0; i < 4; ++i)
#pragma unroll
    for (int j = 0; j < 4; ++j) {
      accg[i][j] = {0.f, 0.f, 0.f, 0.f};
      accu[i][j] = {0.f, 0.f, 0.f, 0.f};
    }

  for (int kt = 0; kt < Hn / 64; ++kt) {
    const int koff = kt << 7;   // 64 bf16 = 128B per K-step
#pragma unroll
    for (int q = 0; q < 4; ++q) {
      GLL16(gA[q] + koff, sA + lbase + (q << 10));
      GLL16(gB[q] + koff, sBg + lbase + (q << 10));
      GLL16(gU[q] + koff, sBu + lbase + (q << 10));
    }
    asm volatile("s_waitcnt vmcnt(0)" ::: "memory");
    __syncthreads();
#pragma unroll
    for (int kk = 0; kk < 2; ++kk) {
      bf16x8 af[4], bg[4], bu[4];
      const int bir = (kk << 6) + ((lane >> 4) << 4);
#pragma unroll
      for (int mi = 0; mi < 4; ++mi) {
        int row = (wm << 6) + (mi << 4) + (lane & 15);
        af[mi] = *(const bf16x8*)(sA + SWZ(row, bir));
      }
#pragma unroll
      for (int ni = 0; ni < 4; ++ni) {
        int n = (wn << 6) + (ni << 4) + (lane & 15);
        bg[ni] = *(const bf16x8*)(sBg + SWZ(n, bir));
        bu[ni] = *(const bf16x8*)(sBu + SWZ(n, bir));
      }
#pragma unroll
      for (int mi = 0; mi < 4; ++mi)
#pragma unroll
        for (int ni = 0; ni < 4; ++ni) {
          accg[mi][ni] = __builtin_amdgcn_mfma_f32_16x16x32_bf16(af[mi], bg[ni], accg[mi][ni], 0, 0, 0);
          accu[mi][ni] = __builtin_amdgcn_mfma_f32_16x16x32_bf16(af[mi], bu[ni], accu[mi][ni], 0, 0, 0);
        }
    }
    __syncthreads();
  }

#pragma unroll
  for (int mi = 0; mi < 4; ++mi)
#pragma unroll
    for (int ni = 0; ni < 4; ++ni)
#pragma unroll
      for (int r = 0; r < 4; ++r) {
        int m = m0 + (wm << 6) + (mi << 4) + ((lane >> 4) << 2) + r;
        int n = n0 + (wn << 6) + (ni << 4) + (lane & 15);
        if (m < cntE) {
          float sc = (mode == 0) ? wgt[(e << 10) + m] : sgate[m];
          float g = accg[mi][ni][r];
          float u = accu[mi][ni][r];
          aout[(size_t)m * N + n] = f2bf(sc * (g / (1.f + __expf(-g))) * u);
        }
      }
}

// ------- fused down GEMM (expert [0,1024) scatter-add + shared [1024,1280) splitK=2)
__global__ __launch_bounds__(256, 2)
void down_kernel(const unsigned short* __restrict__ actE, const unsigned short* __restrict__ actS,
                 const unsigned short* __restrict__ wdT, const unsigned short* __restrict__ sdT,
                 const int* __restrict__ tokList, const int* __restrict__ cnt,
                 float* __restrict__ out) {
  const int bx = blockIdx.x;
  int e, nt, mt, cntE, mode, ktBeg, ktEnd, ldk;
  const unsigned short *aBase, *bBase;
  if (bx < 1024) {
    mode = 0; e = bx >> 7; int r = bx & 127; nt = r >> 3; mt = r & 7;
    cntE = cnt[e];
    if ((mt << 7) >= cntE) return;
    ldk = In; ktBeg = 0; ktEnd = In / 64;
    aBase = actE + (size_t)e * Tn * In + (size_t)(mt << 7) * In;
    bBase = wdT + (size_t)e * Hn * In + (size_t)(nt << 7) * In;
  } else {
    mode = 1; e = 0; int bs = bx - 1024; int split = bs >> 7; int r = bs & 127;
    nt = r >> 3; mt = r & 7; cntE = Tn;
    ldk = ISn; ktBeg = split * 44; ktEnd = ktBeg + 44;
    aBase = actS + (size_t)(mt << 7) * ISn;
    bBase = sdT + (size_t)(nt << 7) * ISn;
  }
  const int m0 = mt << 7, n0 = nt << 7;

  __shared__ char smem[32 * 1024];
  char* sA = smem;
  char* sB = smem + 16 * 1024;

  const int tid = threadIdx.x, lane = tid & 63, wid = tid >> 6;
  const int wm = wid >> 1, wn = wid & 1;
  const int qr = lane >> 3, qc = lane & 7;

  const char *gA[4], *gB[4];
#pragma unroll
  for (int q = 0; q < 4; ++q) {
    int row = (wid << 5) + (q << 3) + qr;
    int chunk = SWZC(row, qc);
    gA[q] = (const char*)(aBase + (size_t)row * ldk) + chunk * 16;
    gB[q] = (const char*)(bBase + (size_t)row * ldk) + chunk * 16;
  }
  const int lbase = wid << 12;

  f32x4 acc[4][4];
#pragma unroll
  for (int i = 0; i < 4; ++i)
#pragma unroll
    for (int j = 0; j < 4; ++j) acc[i][j] = {0.f, 0.f, 0.f, 0.f};

  for (int kt = ktBeg; kt < ktEnd; ++kt) {
    const int koff = kt << 7;
#pragma unroll
    for (int q = 0; q < 4; ++q) {
      GLL16(gA[q] + koff, sA + lbase + (q << 10));
      GLL16(gB[q] + koff, sB + lbase + (q << 10));
    }
    asm volatile("s_waitcnt vmcnt(0)" ::: "memory");
    __syncthreads();
#pragma unroll
    for (int kk = 0; kk < 2; ++kk) {
      bf16x8 af[4], bf[4];
      const int bir = (kk << 6) + ((lane >> 4) << 4);
#pragma unroll
      for (int mi = 0; mi < 4; ++mi) {
        int row = (wm << 6) + (mi << 4) + (lane & 15);
        af[mi] = *(const bf16x8*)(sA + SWZ(row, bir));
      }
#pragma unroll
      for (int ni = 0; ni < 4; ++ni) {
        int n = (wn << 6) + (ni << 4) + (lane & 15);
        bf[ni] = *(const bf16x8*)(sB + SWZ(n, bir));
      }
#pragma unroll
      for (int mi = 0; mi < 4; ++mi)
#pragma unroll
        for (int ni = 0; ni < 4; ++ni)
          acc[mi][ni] = __builtin_amdgcn_mfma_f32_16x16x32_bf16(af[mi], bf[ni], acc[mi][ni], 0, 0, 0);
    }
    __syncthreads();
  }

#pragma unroll
  for (int mi = 0; mi < 4; ++mi)
#pragma unroll
    for (int ni = 0; ni < 4; ++ni)
#pragma unroll
      for (int r = 0; r < 4; ++r) {
        int m = m0 + (wm << 6) + (mi << 4) + ((lane >> 4) << 2) + r;
        int n = n0 + (wn << 6) + (ni << 4) + (lane & 15);
        if (mode == 0) {
          if (m < cntE) {
            int tok = tokList[(e << 10) + m];
            atomicAdd(out + (size_t)tok * Hn + n, acc[mi][ni][r]);
          }
        } else {
          atomicAdd(out + (size_t)m * Hn + n, acc[mi][ni][r]);
        }
      }
}

extern "C" void kernel_launch(void* const* d_in, const int* in_sizes, int n_in,
                              void* d_out, int out_size, void* d_ws, size_t ws_size,
                              hipStream_t stream) {
  const float* x   = (const float*)d_in[0];
  const float* gw  = (const float*)d_in[1];
  const float* wg  = (const float*)d_in[2];
  const float* wu  = (const float*)d_in[3];
  const float* wd  = (const float*)d_in[4];
  const float* sg  = (const float*)d_in[5];
  const float* su  = (const float*)d_in[6];
  const float* sd  = (const float*)d_in[7];
  const float* sgw = (const float*)d_in[8];
  float* out = (float*)d_out;
  float* logits_out = out + (size_t)Tn * Hn;   // final [2,512,2048] then logits [1024,8]

  char* w = (char*)d_ws;
  int*   cnt     = (int*)w;                                // 8 int
  float* sgate   = (float*)(w + 4096);                     // 1024 f32
  int*   tokList = (int*)(w + 8192);                       // 8192 int
  float* wgt     = (float*)(w + 40960);                    // 8192 f32
  unsigned short* u = (unsigned short*)(w + 131072);
  unsigned short* xb   = u;                                // 2,097,152
  unsigned short* actE = xb + (size_t)Tn * Hn;             // 11,534,336
  unsigned short* actS = actE + (size_t)En * Tn * In;      // 5,767,168
  unsigned short* wgT  = actS + (size_t)Tn * ISn;          // 23,068,672
  unsigned short* wuT  = wgT + (size_t)En * In * Hn;       // 23,068,672
  unsigned short* wdT  = wuT + (size_t)En * In * Hn;       // 23,068,672
  unsigned short* sgT  = wdT + (size_t)En * Hn * In;       // 11,534,336
  unsigned short* suT  = sgT + (size_t)ISn * Hn;           // 11,534,336
  unsigned short* sdT  = suT + (size_t)ISn * Hn;           // 11,534,336  (~247 MB total)

  hipMemsetAsync(d_out, 0, (size_t)out_size * sizeof(float), stream);
  hipMemsetAsync(cnt, 0, En * sizeof(int), stream);
  router_kernel<<<Tn, 64, 0, stream>>>(x, gw, sgw, logits_out, sgate, tokList, wgt, cnt);
  cvt_x_kernel<<<(Tn * Hn / 4) / 256, 256, 0, stream>>>(x, xb);
  trans_cvt_kernel<<<25344, 256, 0, stream>>>(wg, wu, wd, sg, su, sd, wgT, wuT, wdT, sgT, suT, sdT);
  gateup_kernel<<<704 + 352, 256, 0, stream>>>(xb, wgT, wuT, sgT, suT, wgt, sgate, tokList, cnt, actE, actS);
  down_kernel<<<1024 + 256, 256, 0, stream>>>(actE, actS, wdT, sdT, tokList, cnt, out);
}